// Round 8
// baseline (140.386 us; speedup 1.0000x reference)
//
#include <hip/hip_runtime.h>
#include <hip/hip_bf16.h>

typedef __hip_bfloat16 bf16;
typedef __attribute__((ext_vector_type(8))) short bf16x8;   // 8 bf16 = 4 VGPR (MFMA A/B frag)
typedef __attribute__((ext_vector_type(4))) short bf16x4;   // 4 bf16 = 8B
typedef __attribute__((ext_vector_type(4))) float f32x4;    // MFMA C/D frag

#define TSEQ   2048
#define DMODEL 1024
#define NHEAD  16
#define KST    2112   // padded key count (2049 real, zero-padded), 33*64
#define SCALE  0.17677669529663687f  // 1/sqrt(32) == sem_scale == geo_scale
#define LN1E4_16 0.5756462732485115f // ln(10000)/16

__device__ __forceinline__ unsigned short f2bf(float f) {
    union { bf16 h; unsigned short u; } x;
    x.h = __float2bfloat16(f);
    return x.u;
}
__device__ __forceinline__ float bf2f(unsigned short u) {
    return __uint_as_float(((unsigned int)u) << 16);
}

__device__ __forceinline__ void gload_lds16(const void* g, void* l) {
    __builtin_amdgcn_global_load_lds(
        (const __attribute__((address_space(1))) void*)g,
        (__attribute__((address_space(3))) void*)l, 16, 0, 0);
}

// ---------------------------------------------------------------------------
// Prep: f32 -> bf16 convert of X
// ---------------------------------------------------------------------------
__global__ __launch_bounds__(256) void convert_x(const float* __restrict__ X,
                                                 unsigned short* __restrict__ Xb)
{
    int i = (blockIdx.x * 256 + threadIdx.x) * 4;
    float4 v = *(const float4*)(X + i);
    ushort4 o;
    o.x = f2bf(v.x); o.y = f2bf(v.y); o.z = f2bf(v.z); o.w = f2bf(v.w);
    *(ushort4*)(Xb + i) = o;
}

// ---------------------------------------------------------------------------
// Prep: all 6 weight transposes in one launch. dst[C][1024] = src[1024][C]^T
// ---------------------------------------------------------------------------
__global__ __launch_bounds__(256) void transpose_all(
    const float* __restrict__ wqs, const float* __restrict__ wks,
    const float* __restrict__ wqg, const float* __restrict__ wkg,
    const float* __restrict__ wv,  const float* __restrict__ wo,
    unsigned short* __restrict__ WcatT, unsigned short* __restrict__ WoT)
{
    __shared__ float T[64][65];
    const float* src; unsigned short* dst; int C;
    switch (blockIdx.z) {
        case 0: src = wqs; dst = WcatT;               C = 512;  break;
        case 1: src = wks; dst = WcatT + 512  * 1024; C = 512;  break;
        case 2: src = wqg; dst = WcatT + 1024 * 1024; C = 512;  break;
        case 3: src = wkg; dst = WcatT + 1536 * 1024; C = 512;  break;
        case 4: src = wv;  dst = WcatT + 2048 * 1024; C = 1024; break;
        default: src = wo; dst = WoT;                 C = 1024; break;
    }
    const int c0 = blockIdx.x * 64;
    if (c0 >= C) return;
    const int r0 = blockIdx.y * 64;
    const int tid = threadIdx.x;
    #pragma unroll
    for (int i = 0; i < 16; ++i) {
        int idx = tid + 256 * i;
        int r = idx >> 6, c = idx & 63;
        T[r][c] = src[(size_t)(r0 + r) * C + c0 + c];
    }
    __syncthreads();
    #pragma unroll
    for (int i = 0; i < 16; ++i) {
        int idx = tid + 256 * i;
        int cc = idx >> 6, rr = idx & 63;
        dst[(size_t)(c0 + cc) * 1024 + r0 + rr] = f2bf(T[rr][cc]);
    }
}

// ---------------------------------------------------------------------------
// Prep: fill null rows (fk=0) and zero pads (fk in [2049,2112)) of Kc / Vg.
// ---------------------------------------------------------------------------
__global__ __launch_bounds__(256) void init_null(
    const float* __restrict__ ksn, const float* __restrict__ kgn,
    const float* __restrict__ vn,
    unsigned short* __restrict__ Kc, unsigned short* __restrict__ Vg)
{
    const int h = blockIdx.x;
    const int tid = threadIdx.x;
    const int d = tid & 63, g = tid >> 6;
    if (g == 0)
        Kc[((size_t)h * KST + 0) * 64 + d] =
            f2bf(d < 32 ? ksn[h * 32 + d] : kgn[h * 32 + d - 32]);
    if (g == 1)
        Vg[((size_t)h * 64 + d) * KST + 0] = f2bf(vn[h * 64 + d]);
    for (int fk = 2049 + g; fk < KST; fk += 4) {
        Kc[((size_t)h * KST + fk) * 64 + d] = 0;
        Vg[((size_t)h * 64 + d) * KST + fk] = 0;
    }
}

// ---------------------------------------------------------------------------
// Fused projection GEMM: 64x128 tile (grid 24x32 = 768 blocks), BK=32.
// Epilogue writes directly into attention layouts (Qc pre-scaled, RoPE fused).
// ---------------------------------------------------------------------------
__global__ __launch_bounds__(256) void gemm_proj_fused(
    const unsigned short* __restrict__ A,   // Xb [2048][1024]
    const unsigned short* __restrict__ Bt,  // WcatT [3072][1024]
    unsigned short* __restrict__ Qc,
    unsigned short* __restrict__ Kc,
    unsigned short* __restrict__ Vg)
{
    __shared__ __align__(16) unsigned short Abuf[64 * 32];
    __shared__ __align__(16) unsigned short Bbuf[128 * 32];
    const int n0 = blockIdx.x * 128, m0 = blockIdx.y * 64;
    const int tid = threadIdx.x, l = tid & 63, wv = tid >> 6;
    const int wr = wv >> 1, wc = wv & 1;      // wave tile: 32 rows x 64 cols
    const int lr = l & 15, lg = l >> 4, kf = lg * 8;

    const int arow = wv * 16 + (l >> 2);
    const int aseg = (l & 3) * 8;

    f32x4 acc[2][4];
    #pragma unroll
    for (int i = 0; i < 2; ++i)
        #pragma unroll
        for (int j = 0; j < 4; ++j) acc[i][j] = (f32x4){0.f, 0.f, 0.f, 0.f};

    for (int k0 = 0; k0 < 1024; k0 += 32) {
        gload_lds16(A + (size_t)(m0 + arow) * 1024 + k0 + aseg, &Abuf[wv * 512]);
        #pragma unroll
        for (int it = 0; it < 2; ++it) {
            int brow = it * 64 + wv * 16 + (l >> 2);
            gload_lds16(Bt + (size_t)(n0 + brow) * 1024 + k0 + aseg,
                        &Bbuf[(it * 256 + wv * 64) * 8]);
        }
        __syncthreads();
        bf16x8 af[2], bfv[4];
        #pragma unroll
        for (int mf = 0; mf < 2; ++mf)
            af[mf] = *(const bf16x8*)&Abuf[(wr * 32 + mf * 16 + lr) * 32 + kf];
        #pragma unroll
        for (int nf = 0; nf < 4; ++nf)
            bfv[nf] = *(const bf16x8*)&Bbuf[(wc * 64 + nf * 16 + lr) * 32 + kf];
        #pragma unroll
        for (int mf = 0; mf < 2; ++mf)
            #pragma unroll
            for (int nf = 0; nf < 4; ++nf)
                acc[mf][nf] = __builtin_amdgcn_mfma_f32_16x16x32_bf16(
                    af[mf], bfv[nf], acc[mf][nf], 0, 0, 0);
        __syncthreads();
    }

    const int sec = n0 >> 9;   // 0 qs | 1 ks | 2 qg | 3 kg | 4,5 v
    if (sec <= 1) {
        unsigned short* dst = (sec == 0) ? Qc : Kc;
        const int tstr  = (sec == 0) ? TSEQ : KST;
        const int fkoff = (sec == 0) ? 0 : 1;
        const float sc  = (sec == 0) ? SCALE : 1.0f;
        #pragma unroll
        for (int mf = 0; mf < 2; ++mf)
            #pragma unroll
            for (int nf = 0; nf < 4; ++nf) {
                int col = (n0 & 511) + wc * 64 + nf * 16 + lr;
                int h = col >> 5, d = col & 31;
                #pragma unroll
                for (int reg = 0; reg < 4; ++reg) {
                    int q = m0 + wr * 32 + mf * 16 + lg * 4 + reg;
                    dst[((size_t)h * tstr + q + fkoff) * 64 + d] =
                        f2bf(acc[mf][nf][reg] * sc);
                }
            }
    } else if (sec <= 3) {
        unsigned short* dst = (sec == 2) ? Qc : Kc;
        const int tstr  = (sec == 2) ? TSEQ : KST;
        const int fkoff = (sec == 2) ? 0 : 1;
        const float sc  = (sec == 2) ? SCALE : 1.0f;
        const float invf = __expf(-(float)lr * LN1E4_16);
        #pragma unroll
        for (int mf = 0; mf < 2; ++mf)
            #pragma unroll
            for (int reg = 0; reg < 4; ++reg) {
                int q = m0 + wr * 32 + mf * 16 + lg * 4 + reg;
                float s, c;
                __sincosf((float)q * invf, &s, &c);
                #pragma unroll
                for (int nfp = 0; nfp < 2; ++nfp) {
                    int nf0 = nfp * 2;
                    int colbase = (n0 & 511) + wc * 64 + nf0 * 16;
                    int h = colbase >> 5;
                    float x1 = acc[mf][nf0][reg], x2 = acc[mf][nf0 + 1][reg];
                    size_t base = ((size_t)h * tstr + q + fkoff) * 64 + 32;
                    dst[base + lr]      = f2bf((x1 * c - x2 * s) * sc);
                    dst[base + lr + 16] = f2bf((x2 * c + x1 * s) * sc);
                }
            }
    } else {
        #pragma unroll
        for (int nf = 0; nf < 4; ++nf) {
            int colr = (n0 - 2048) + wc * 64 + nf * 16 + lr;
            int h = colr >> 6, dv = colr & 63;
            size_t rowbase = ((size_t)h * 64 + dv) * KST;
            #pragma unroll
            for (int mf = 0; mf < 2; ++mf)
                #pragma unroll
                for (int reg = 0; reg < 4; ++reg) {
                    int q = m0 + wr * 32 + mf * 16 + lg * 4 + reg;
                    Vg[rowbase + q + 1] = f2bf(acc[mf][nf][reg]);
                }
        }
    }
}

// ---------------------------------------------------------------------------
// Output GEMM: 64x64 tile (grid 16x32 = 512 blocks), BK=32.
// ---------------------------------------------------------------------------
__global__ __launch_bounds__(256) void gemm_out(const unsigned short* __restrict__ A,
                                                const unsigned short* __restrict__ Bt,
                                                float* __restrict__ C)
{
    __shared__ __align__(16) unsigned short Abuf[64 * 32];
    __shared__ __align__(16) unsigned short Bbuf[64 * 32];
    const int n0 = blockIdx.x * 64, m0 = blockIdx.y * 64;
    const int tid = threadIdx.x, l = tid & 63, wv = tid >> 6;
    const int wr = wv >> 1, wc = wv & 1;      // wave tile: 32 x 32
    const int lr = l & 15, lg = l >> 4, kf = lg * 8;

    const int arow = wv * 16 + (l >> 2);
    const int aseg = (l & 3) * 8;

    f32x4 acc[2][2];
    #pragma unroll
    for (int i = 0; i < 2; ++i)
        #pragma unroll
        for (int j = 0; j < 2; ++j) acc[i][j] = (f32x4){0.f, 0.f, 0.f, 0.f};

    for (int k0 = 0; k0 < 1024; k0 += 32) {
        gload_lds16(A  + (size_t)(m0 + arow) * 1024 + k0 + aseg, &Abuf[wv * 512]);
        gload_lds16(Bt + (size_t)(n0 + arow) * 1024 + k0 + aseg, &Bbuf[wv * 512]);
        __syncthreads();
        bf16x8 af[2], bfv[2];
        #pragma unroll
        for (int mf = 0; mf < 2; ++mf)
            af[mf] = *(const bf16x8*)&Abuf[(wr * 32 + mf * 16 + lr) * 32 + kf];
        #pragma unroll
        for (int nf = 0; nf < 2; ++nf)
            bfv[nf] = *(const bf16x8*)&Bbuf[(wc * 32 + nf * 16 + lr) * 32 + kf];
        #pragma unroll
        for (int mf = 0; mf < 2; ++mf)
            #pragma unroll
            for (int nf = 0; nf < 2; ++nf)
                acc[mf][nf] = __builtin_amdgcn_mfma_f32_16x16x32_bf16(
                    af[mf], bfv[nf], acc[mf][nf], 0, 0, 0);
        __syncthreads();
    }
    #pragma unroll
    for (int mf = 0; mf < 2; ++mf)
        #pragma unroll
        for (int nf = 0; nf < 2; ++nf)
            #pragma unroll
            for (int reg = 0; reg < 4; ++reg) {
                int row = m0 + wr * 32 + mf * 16 + lg * 4 + reg;
                int col = n0 + wc * 32 + nf * 16 + lr;
                C[(size_t)row * DMODEL + col] = acc[mf][nf][reg];
            }
}

// ---------------------------------------------------------------------------
// Wave-dataflow MFMA flash attention: NO barriers, NO K/V LDS.
// Each WAVE independently owns (head, 16 q-rows, kv-part). K and V^T MFMA
// fragments are loaded straight from global (L2-resident) into registers with
// per-lane fragment addressing. Software pipeline per tile:
//   issue V(t) -> QK(t) (K regs from prev iter) -> softmax -> issue K(t+1)
//   -> PV(t).  Compiler emits counted vmcnt from register dependencies.
// Ps is a wave-local LDS slice (same-wave write/read, lgkm-guarded).
// Work split: parts capped at 11 tiles; nparts = 1 (qsl<43), 2 (<87), 3.
// ---------------------------------------------------------------------------
__global__ __launch_bounds__(256, 3) void attn_wave(
    const unsigned short* __restrict__ Qc,
    const unsigned short* __restrict__ Kc,
    const unsigned short* __restrict__ Vg,
    unsigned short* __restrict__ attnO,
    unsigned short* __restrict__ Opart,
    float2* __restrict__ ml)
{
    __shared__ __align__(16) unsigned short Ps[4][16 * 64];

    const int tid = threadIdx.x, l = tid & 63, w = tid >> 6;
    const int lr = l & 15, lg = l >> 4;

    const int g = blockIdx.x * 4 + w;      // wave-item id, < 4064
    const int h = g & 15;
    const int p = 253 - (g >> 4);          // heavy-first
    int qsl, part, nparts;
    if (p < 43)       { qsl = p; part = 0; nparts = 1; }
    else if (p < 131) { int j = p - 43; qsl = 43 + (j >> 1); part = j & 1; nparts = 2; }
    else              { int j = p - 131; qsl = 87 + j / 3; part = j % 3; nparts = 3; }

    const int nt = (qsl + 1) / 4 + 1;      // causal tile count for this q-slice
    const int base = nt / nparts, rem = nt % nparts;
    const int t0 = part * base + (part < rem ? part : rem);
    const int t1 = t0 + base + (part < rem ? 1 : 0);

    const int q = qsl * 16 + lr;           // this lane's query row

    // Q fragment (B-operand): 8 consecutive d at lg*8 for row q
    bf16x8 qa0 = *(const bf16x8*)&Qc[((size_t)h * TSEQ + q) * 64 + lg * 8];
    bf16x8 qa1 = *(const bf16x8*)&Qc[((size_t)h * TSEQ + q) * 64 + 32 + lg * 8];

    const unsigned short* Kh = Kc + (((size_t)h * KST) << 6);
    const unsigned short* Vh = Vg + (size_t)h * 64 * KST;

    bf16x8 kr[8], vr[8];
#define LOADK(fk0_) do {                                                       \
        _Pragma("unroll")                                                      \
        for (int ks = 0; ks < 2; ++ks)                                         \
            _Pragma("unroll")                                                  \
            for (int nf = 0; nf < 4; ++nf)                                     \
                kr[ks * 4 + nf] = *(const bf16x8*)                             \
                    &Kh[(size_t)((fk0_) + nf * 16 + lr) * 64 + lg * 8 + ks * 32]; \
    } while (0)
#define LOADV(fk0_) do {                                                       \
        _Pragma("unroll")                                                      \
        for (int ks = 0; ks < 2; ++ks)                                         \
            _Pragma("unroll")                                                  \
            for (int nf = 0; nf < 4; ++nf)                                     \
                vr[ks * 4 + nf] = *(const bf16x8*)                             \
                    &Vh[(size_t)(nf * 16 + lr) * KST + (fk0_) + lg * 8 + ks * 32]; \
    } while (0)

    f32x4 o[4];
    #pragma unroll
    for (int i = 0; i < 4; ++i) o[i] = (f32x4){0.f, 0.f, 0.f, 0.f};
    float m = -1e30f, ll = 0.0f;

    LOADK(t0 * 64);
    for (int kb = t0; kb < t1; ++kb) {
        const int fk0 = kb * 64;
        LOADV(fk0);                         // in flight during QK + softmax

        // ---- S^T = K Q^T : lane holds S[kk = nf*16 + lg*4 + reg][q]
        f32x4 sa[4];
        #pragma unroll
        for (int i = 0; i < 4; ++i) sa[i] = (f32x4){0.f, 0.f, 0.f, 0.f};
        __builtin_amdgcn_s_setprio(1);
        #pragma unroll
        for (int ks = 0; ks < 2; ++ks) {
            bf16x8 qa = ks ? qa1 : qa0;
            #pragma unroll
            for (int nf = 0; nf < 4; ++nf)
                sa[nf] = __builtin_amdgcn_mfma_f32_16x16x32_bf16(
                    kr[ks * 4 + nf], qa, sa[nf], 0, 0, 0);
        }
        __builtin_amdgcn_s_setprio(0);

        // ---- mask; in-lane tree max + 2-stage shfl (Q pre-scaled by SCALE)
        float sv[4][4];
        float mt = -1e30f;
        #pragma unroll
        for (int nf = 0; nf < 4; ++nf)
            #pragma unroll
            for (int reg = 0; reg < 4; ++reg) {
                int fk = fk0 + nf * 16 + lg * 4 + reg;
                float val = (fk <= q + 1) ? sa[nf][reg] : -1e9f;
                sv[nf][reg] = val;
                mt = fmaxf(mt, val);
            }
        mt = fmaxf(mt, __shfl_xor(mt, 16, 64));
        mt = fmaxf(mt, __shfl_xor(mt, 32, 64));
        float mn = fmaxf(m, mt);
        float alpha = __expf(m - mn);
        m = mn;
        float rs = 0.0f;
        #pragma unroll
        for (int nf = 0; nf < 4; ++nf)
            #pragma unroll
            for (int reg = 0; reg < 4; ++reg) {
                float pv = __expf(sv[nf][reg] - m);
                sv[nf][reg] = pv;
                rs += pv;
            }
        rs += __shfl_xor(rs, 16, 64);
        rs += __shfl_xor(rs, 32, 64);
        ll = ll * alpha + rs;
        #pragma unroll
        for (int nf = 0; nf < 4; ++nf)
            #pragma unroll
            for (int reg = 0; reg < 4; ++reg)
                o[nf][reg] *= alpha;

        // ---- P -> bf16 -> wave-local Ps slice (swizzled, packed b64)
        #pragma unroll
        for (int nf = 0; nf < 4; ++nf) {
            bf16x4 pk;
            pk[0] = f2bf(sv[nf][0]); pk[1] = f2bf(sv[nf][1]);
            pk[2] = f2bf(sv[nf][2]); pk[3] = f2bf(sv[nf][3]);
            int kk0 = nf * 16 + lg * 4;
            *(bf16x4*)&Ps[w][lr * 64 + (kk0 ^ ((lr & 7) << 3))] = pk;
        }

        // ---- prefetch next K tile (WAR-safe: QK already consumed kr)
        {
            int tn = (kb + 1 < t1) ? kb + 1 : kb;
            LOADK(tn * 64);
        }

        // ---- O^T += V^T P^T
        __builtin_amdgcn_s_setprio(1);
        #pragma unroll
        for (int ks = 0; ks < 2; ++ks) {
            int kk0 = lg * 8 + ks * 32;
            bf16x8 pa = *(const bf16x8*)&Ps[w][lr * 64 + (kk0 ^ ((lr & 7) << 3))];
            #pragma unroll
            for (int nf = 0; nf < 4; ++nf)
                o[nf] = __builtin_amdgcn_mfma_f32_16x16x32_bf16(
                    vr[ks * 4 + nf], pa, o[nf], 0, 0, 0);
        }
        __builtin_amdgcn_s_setprio(0);
    }
#undef LOADK
#undef LOADV

    const float invl = 1.0f / ll;
    if (nparts == 1) {
        #pragma unroll
        for (int nf = 0; nf < 4; ++nf) {
            ushort4 ov;
            ov.x = f2bf(o[nf][0] * invl); ov.y = f2bf(o[nf][1] * invl);
            ov.z = f2bf(o[nf][2] * invl); ov.w = f2bf(o[nf][3] * invl);
            *(ushort4*)&attnO[(size_t)q * DMODEL + h * 64 + nf * 16 + lg * 4] = ov;
        }
    } else {
        int local = (nparts == 2) ? (qsl - 43) * 2 + part
                                  : 88 + (qsl - 87) * 3 + part;
        int sidx = h * 211 + local;
        unsigned short* Od = Opart + (size_t)sidx * 1024;
        #pragma unroll
        for (int nf = 0; nf < 4; ++nf) {
            ushort4 ov;
            ov.x = f2bf(o[nf][0] * invl); ov.y = f2bf(o[nf][1] * invl);
            ov.z = f2bf(o[nf][2] * invl); ov.w = f2bf(o[nf][3] * invl);
            *(ushort4*)&Od[lr * 64 + nf * 16 + lg * 4] = ov;
        }
        if (lg == 0)
            ml[sidx * 16 + lr] = make_float2(m, ll);
    }
}

// ---------------------------------------------------------------------------
// Combine split partials: one block per (h, qsl >= 43). nparts = 2 or 3.
// ---------------------------------------------------------------------------
__global__ __launch_bounds__(256) void combine_wave(
    const unsigned short* __restrict__ Opart,
    const float2* __restrict__ ml,
    unsigned short* __restrict__ attnO)
{
    const int bx = blockIdx.x;             // 16 * 85
    const int h = bx / 85, qsl = 43 + bx % 85;
    const int nparts = (qsl < 87) ? 2 : 3;
    const int local0 = (qsl < 87) ? (qsl - 43) * 2 : 88 + (qsl - 87) * 3;
    const int sidx0 = h * 211 + local0;
    const int t = threadIdx.x;
    const int r = t >> 4, dv0 = (t & 15) * 4;

    float2 m0 = ml[(sidx0 + 0) * 16 + r];
    float2 m1 = ml[(sidx0 + 1) * 16 + r];
    float2 m2 = (nparts == 3) ? ml[(sidx0 + 2) * 16 + r] : make_float2(-1e30f, 0.f);
    float mm = fmaxf(fmaxf(m0.x, m1.x), m2.x);
    float w0 = m0.y * __expf(m0.x - mm);
    float w1 = m1.y * __expf(m1.x - mm);
    float w2 = m2.y * __expf(m2.x - mm);
    float inv = 1.0f / (w0 + w1 + w2);

    const unsigned short* O0 = Opart + (size_t)(sidx0 + 0) * 1024 + r * 64 + dv0;
    const unsigned short* O1 = Opart + (size_t)(sidx0 + 1) * 1024 + r * 64 + dv0;
    const unsigned short* O2 = (nparts == 3)
        ? Opart + (size_t)(sidx0 + 2) * 1024 + r * 64 + dv0 : O0;   // w2=0 if absent

    ushort4 a = *(const ushort4*)O0;
    ushort4 b = *(const ushort4*)O1;
    ushort4 c = *(const ushort4*)O2;
    ushort4 ov;
    ov.x = f2bf((w0 * bf2f(a.x) + w1 * bf2f(b.x) + w2 * bf2f(c.x)) * inv);
    ov.y = f2bf((w0 * bf2f(a.y) + w1 * bf2f(b.y) + w2 * bf2f(c.y)) * inv);
    ov.z = f2bf((w0 * bf2f(a.z) + w1 * bf2f(b.z) + w2 * bf2f(c.z)) * inv);
    ov.w = f2bf((w0 * bf2f(a.w) + w1 * bf2f(b.w) + w2 * bf2f(c.w)) * inv);
    int q = qsl * 16 + r;
    *(ushort4*)&attnO[(size_t)q * DMODEL + h * 64 + dv0] = ov;
}

// ---------------------------------------------------------------------------
extern "C" void kernel_launch(void* const* d_in, const int* in_sizes, int n_in,
                              void* d_out, int out_size, void* d_ws, size_t ws_size,
                              hipStream_t stream)
{
    const float* x      = (const float*)d_in[0];
    const float* wq_sem = (const float*)d_in[1];
    const float* wk_sem = (const float*)d_in[2];
    const float* wq_geo = (const float*)d_in[3];
    const float* wk_geo = (const float*)d_in[4];
    const float* wv     = (const float*)d_in[5];
    const float* wo     = (const float*)d_in[6];
    const float* ksn    = (const float*)d_in[7];
    const float* kgn    = (const float*)d_in[8];
    const float* vn     = (const float*)d_in[9];
    float* out = (float*)d_out;

    // Workspace (peak 31.3 MiB, under 33.6 MB proven in round 2):
    //  [0,        4.19M)  Xb -> attnO
    //  [4.19M,   10.49M)  WcatT
    //  [10.49M,  12.58M)  WoT
    //  [12.58M,  16.78M)  Qc  [16][2048][64]
    //  [16.78M,  21.10M)  Kc  [16][2112][64]
    //  [21.10M,  25.43M)  Vg  [16][64][2112]
    //  [25.43M,  32.34M)  Opart [3376][16][64]
    //  [32.34M,  32.77M)  ml  float2 [3376][16]
    char* ws = (char*)d_ws;
    unsigned short* Xb    = (unsigned short*)(ws);
    unsigned short* attnO = (unsigned short*)(ws);
    unsigned short* WcatT = (unsigned short*)(ws + 4194304);
    unsigned short* WoT   = (unsigned short*)(ws + 10485760);
    unsigned short* Qc    = (unsigned short*)(ws + 12582912);
    unsigned short* Kc    = (unsigned short*)(ws + 16777216);
    unsigned short* Vg    = (unsigned short*)(ws + 21102592);
    unsigned short* Opart = (unsigned short*)(ws + 25427968);
    float2*         ml    = (float2*)(ws + 32342016);

    convert_x<<<2048, 256, 0, stream>>>(x, Xb);
    transpose_all<<<dim3(16, 16, 6), 256, 0, stream>>>(
        wq_sem, wk_sem, wq_geo, wk_geo, wv, wo, WcatT, WoT);
    init_null<<<16, 256, 0, stream>>>(ksn, kgn, vn, Kc, Vg);

    gemm_proj_fused<<<dim3(24, 32), 256, 0, stream>>>(Xb, WcatT, Qc, Kc, Vg);

    attn_wave<<<1016, 256, 0, stream>>>(Qc, Kc, Vg, attnO, Opart, ml);
    combine_wave<<<16 * 85, 256, 0, stream>>>(Opart, ml, attnO);

    gemm_out<<<dim3(16, 32), 256, 0, stream>>>(attnO, WoT, out);
}

// Round 9
// 95.318 us; speedup vs baseline: 1.4728x; 1.4728x over previous
//
#include <hip/hip_runtime.h>
#include <hip/hip_bf16.h>

typedef __hip_bfloat16 bf16;
typedef __attribute__((ext_vector_type(8))) short bf16x8;   // 8 bf16 = 4 VGPR (MFMA A/B frag)
typedef __attribute__((ext_vector_type(4))) short bf16x4;   // 4 bf16 = 8B
typedef __attribute__((ext_vector_type(4))) float f32x4;    // MFMA C/D frag

#define TSEQ   2048
#define DMODEL 1024
#define NHEAD  16
#define KST    2112   // padded key count (2049 real, zero-padded), 33*64
#define SCALE  0.17677669529663687f  // 1/sqrt(32) == sem_scale == geo_scale
#define LN1E4_16 0.5756462732485115f // ln(10000)/16

__device__ __forceinline__ unsigned short f2bf(float f) {
    union { bf16 h; unsigned short u; } x;
    x.h = __float2bfloat16(f);
    return x.u;
}
__device__ __forceinline__ float bf2f(unsigned short u) {
    return __uint_as_float(((unsigned int)u) << 16);
}

__device__ __forceinline__ void gload_lds16(const void* g, void* l) {
    __builtin_amdgcn_global_load_lds(
        (const __attribute__((address_space(1))) void*)g,
        (__attribute__((address_space(3))) void*)l, 16, 0, 0);
}

// ---------------------------------------------------------------------------
// Prep: f32 -> bf16 convert of X
// ---------------------------------------------------------------------------
__global__ __launch_bounds__(256) void convert_x(const float* __restrict__ X,
                                                 unsigned short* __restrict__ Xb)
{
    int i = (blockIdx.x * 256 + threadIdx.x) * 4;
    float4 v = *(const float4*)(X + i);
    ushort4 o;
    o.x = f2bf(v.x); o.y = f2bf(v.y); o.z = f2bf(v.z); o.w = f2bf(v.w);
    *(ushort4*)(Xb + i) = o;
}

// ---------------------------------------------------------------------------
// Prep: all 6 weight transposes in one launch. dst[C][1024] = src[1024][C]^T
// ---------------------------------------------------------------------------
__global__ __launch_bounds__(256) void transpose_all(
    const float* __restrict__ wqs, const float* __restrict__ wks,
    const float* __restrict__ wqg, const float* __restrict__ wkg,
    const float* __restrict__ wv,  const float* __restrict__ wo,
    unsigned short* __restrict__ WcatT, unsigned short* __restrict__ WoT)
{
    __shared__ float T[64][65];
    const float* src; unsigned short* dst; int C;
    switch (blockIdx.z) {
        case 0: src = wqs; dst = WcatT;               C = 512;  break;
        case 1: src = wks; dst = WcatT + 512  * 1024; C = 512;  break;
        case 2: src = wqg; dst = WcatT + 1024 * 1024; C = 512;  break;
        case 3: src = wkg; dst = WcatT + 1536 * 1024; C = 512;  break;
        case 4: src = wv;  dst = WcatT + 2048 * 1024; C = 1024; break;
        default: src = wo; dst = WoT;                 C = 1024; break;
    }
    const int c0 = blockIdx.x * 64;
    if (c0 >= C) return;
    const int r0 = blockIdx.y * 64;
    const int tid = threadIdx.x;
    #pragma unroll
    for (int i = 0; i < 16; ++i) {
        int idx = tid + 256 * i;
        int r = idx >> 6, c = idx & 63;
        T[r][c] = src[(size_t)(r0 + r) * C + c0 + c];
    }
    __syncthreads();
    #pragma unroll
    for (int i = 0; i < 16; ++i) {
        int idx = tid + 256 * i;
        int cc = idx >> 6, rr = idx & 63;
        dst[(size_t)(c0 + cc) * 1024 + r0 + rr] = f2bf(T[rr][cc]);
    }
}

// ---------------------------------------------------------------------------
// Prep: fill null rows (fk=0) and zero pads (fk in [2049,2112)) of Kc / Vg.
// ---------------------------------------------------------------------------
__global__ __launch_bounds__(256) void init_null(
    const float* __restrict__ ksn, const float* __restrict__ kgn,
    const float* __restrict__ vn,
    unsigned short* __restrict__ Kc, unsigned short* __restrict__ Vg)
{
    const int h = blockIdx.x;
    const int tid = threadIdx.x;
    const int d = tid & 63, g = tid >> 6;
    if (g == 0)
        Kc[((size_t)h * KST + 0) * 64 + d] =
            f2bf(d < 32 ? ksn[h * 32 + d] : kgn[h * 32 + d - 32]);
    if (g == 1)
        Vg[((size_t)h * 64 + d) * KST + 0] = f2bf(vn[h * 64 + d]);
    for (int fk = 2049 + g; fk < KST; fk += 4) {
        Kc[((size_t)h * KST + fk) * 64 + d] = 0;
        Vg[((size_t)h * 64 + d) * KST + fk] = 0;
    }
}

// ---------------------------------------------------------------------------
// Fused projection GEMM: 64x128 tile (grid 24x32 = 768 blocks), BK=32.
// Epilogue writes directly into attention layouts (Qc pre-scaled, RoPE fused).
// ---------------------------------------------------------------------------
__global__ __launch_bounds__(256) void gemm_proj_fused(
    const unsigned short* __restrict__ A,   // Xb [2048][1024]
    const unsigned short* __restrict__ Bt,  // WcatT [3072][1024]
    unsigned short* __restrict__ Qc,
    unsigned short* __restrict__ Kc,
    unsigned short* __restrict__ Vg)
{
    __shared__ __align__(16) unsigned short Abuf[64 * 32];
    __shared__ __align__(16) unsigned short Bbuf[128 * 32];
    const int n0 = blockIdx.x * 128, m0 = blockIdx.y * 64;
    const int tid = threadIdx.x, l = tid & 63, wv = tid >> 6;
    const int wr = wv >> 1, wc = wv & 1;      // wave tile: 32 rows x 64 cols
    const int lr = l & 15, lg = l >> 4, kf = lg * 8;

    const int arow = wv * 16 + (l >> 2);
    const int aseg = (l & 3) * 8;

    f32x4 acc[2][4];
    #pragma unroll
    for (int i = 0; i < 2; ++i)
        #pragma unroll
        for (int j = 0; j < 4; ++j) acc[i][j] = (f32x4){0.f, 0.f, 0.f, 0.f};

    for (int k0 = 0; k0 < 1024; k0 += 32) {
        gload_lds16(A + (size_t)(m0 + arow) * 1024 + k0 + aseg, &Abuf[wv * 512]);
        #pragma unroll
        for (int it = 0; it < 2; ++it) {
            int brow = it * 64 + wv * 16 + (l >> 2);
            gload_lds16(Bt + (size_t)(n0 + brow) * 1024 + k0 + aseg,
                        &Bbuf[(it * 256 + wv * 64) * 8]);
        }
        __syncthreads();
        bf16x8 af[2], bfv[4];
        #pragma unroll
        for (int mf = 0; mf < 2; ++mf)
            af[mf] = *(const bf16x8*)&Abuf[(wr * 32 + mf * 16 + lr) * 32 + kf];
        #pragma unroll
        for (int nf = 0; nf < 4; ++nf)
            bfv[nf] = *(const bf16x8*)&Bbuf[(wc * 64 + nf * 16 + lr) * 32 + kf];
        #pragma unroll
        for (int mf = 0; mf < 2; ++mf)
            #pragma unroll
            for (int nf = 0; nf < 4; ++nf)
                acc[mf][nf] = __builtin_amdgcn_mfma_f32_16x16x32_bf16(
                    af[mf], bfv[nf], acc[mf][nf], 0, 0, 0);
        __syncthreads();
    }

    const int sec = n0 >> 9;   // 0 qs | 1 ks | 2 qg | 3 kg | 4,5 v
    if (sec <= 1) {
        unsigned short* dst = (sec == 0) ? Qc : Kc;
        const int tstr  = (sec == 0) ? TSEQ : KST;
        const int fkoff = (sec == 0) ? 0 : 1;
        const float sc  = (sec == 0) ? SCALE : 1.0f;
        #pragma unroll
        for (int mf = 0; mf < 2; ++mf)
            #pragma unroll
            for (int nf = 0; nf < 4; ++nf) {
                int col = (n0 & 511) + wc * 64 + nf * 16 + lr;
                int h = col >> 5, d = col & 31;
                #pragma unroll
                for (int reg = 0; reg < 4; ++reg) {
                    int q = m0 + wr * 32 + mf * 16 + lg * 4 + reg;
                    dst[((size_t)h * tstr + q + fkoff) * 64 + d] =
                        f2bf(acc[mf][nf][reg] * sc);
                }
            }
    } else if (sec <= 3) {
        unsigned short* dst = (sec == 2) ? Qc : Kc;
        const int tstr  = (sec == 2) ? TSEQ : KST;
        const int fkoff = (sec == 2) ? 0 : 1;
        const float sc  = (sec == 2) ? SCALE : 1.0f;
        const float invf = __expf(-(float)lr * LN1E4_16);
        #pragma unroll
        for (int mf = 0; mf < 2; ++mf)
            #pragma unroll
            for (int reg = 0; reg < 4; ++reg) {
                int q = m0 + wr * 32 + mf * 16 + lg * 4 + reg;
                float s, c;
                __sincosf((float)q * invf, &s, &c);
                #pragma unroll
                for (int nfp = 0; nfp < 2; ++nfp) {
                    int nf0 = nfp * 2;
                    int colbase = (n0 & 511) + wc * 64 + nf0 * 16;
                    int h = colbase >> 5;
                    float x1 = acc[mf][nf0][reg], x2 = acc[mf][nf0 + 1][reg];
                    size_t base = ((size_t)h * tstr + q + fkoff) * 64 + 32;
                    dst[base + lr]      = f2bf((x1 * c - x2 * s) * sc);
                    dst[base + lr + 16] = f2bf((x2 * c + x1 * s) * sc);
                }
            }
    } else {
        #pragma unroll
        for (int nf = 0; nf < 4; ++nf) {
            int colr = (n0 - 2048) + wc * 64 + nf * 16 + lr;
            int h = colr >> 6, dv = colr & 63;
            size_t rowbase = ((size_t)h * 64 + dv) * KST;
            #pragma unroll
            for (int mf = 0; mf < 2; ++mf)
                #pragma unroll
                for (int reg = 0; reg < 4; ++reg) {
                    int q = m0 + wr * 32 + mf * 16 + lg * 4 + reg;
                    Vg[rowbase + q + 1] = f2bf(acc[mf][nf][reg]);
                }
        }
    }
}

// ---------------------------------------------------------------------------
// Output GEMM: 64x64 tile (grid 16x32 = 512 blocks), BK=32.
// ---------------------------------------------------------------------------
__global__ __launch_bounds__(256) void gemm_out(const unsigned short* __restrict__ A,
                                                const unsigned short* __restrict__ Bt,
                                                float* __restrict__ C)
{
    __shared__ __align__(16) unsigned short Abuf[64 * 32];
    __shared__ __align__(16) unsigned short Bbuf[64 * 32];
    const int n0 = blockIdx.x * 64, m0 = blockIdx.y * 64;
    const int tid = threadIdx.x, l = tid & 63, wv = tid >> 6;
    const int wr = wv >> 1, wc = wv & 1;      // wave tile: 32 x 32
    const int lr = l & 15, lg = l >> 4, kf = lg * 8;

    const int arow = wv * 16 + (l >> 2);
    const int aseg = (l & 3) * 8;

    f32x4 acc[2][2];
    #pragma unroll
    for (int i = 0; i < 2; ++i)
        #pragma unroll
        for (int j = 0; j < 2; ++j) acc[i][j] = (f32x4){0.f, 0.f, 0.f, 0.f};

    for (int k0 = 0; k0 < 1024; k0 += 32) {
        gload_lds16(A  + (size_t)(m0 + arow) * 1024 + k0 + aseg, &Abuf[wv * 512]);
        gload_lds16(Bt + (size_t)(n0 + arow) * 1024 + k0 + aseg, &Bbuf[wv * 512]);
        __syncthreads();
        bf16x8 af[2], bfv[2];
        #pragma unroll
        for (int mf = 0; mf < 2; ++mf)
            af[mf] = *(const bf16x8*)&Abuf[(wr * 32 + mf * 16 + lr) * 32 + kf];
        #pragma unroll
        for (int nf = 0; nf < 2; ++nf)
            bfv[nf] = *(const bf16x8*)&Bbuf[(wc * 32 + nf * 16 + lr) * 32 + kf];
        #pragma unroll
        for (int mf = 0; mf < 2; ++mf)
            #pragma unroll
            for (int nf = 0; nf < 2; ++nf)
                acc[mf][nf] = __builtin_amdgcn_mfma_f32_16x16x32_bf16(
                    af[mf], bfv[nf], acc[mf][nf], 0, 0, 0);
        __syncthreads();
    }
    #pragma unroll
    for (int mf = 0; mf < 2; ++mf)
        #pragma unroll
        for (int nf = 0; nf < 2; ++nf)
            #pragma unroll
            for (int reg = 0; reg < 4; ++reg) {
                int row = m0 + wr * 32 + mf * 16 + lg * 4 + reg;
                int col = n0 + wc * 32 + nf * 16 + lr;
                C[(size_t)row * DMODEL + col] = acc[mf][nf][reg];
            }
}

// ---------------------------------------------------------------------------
// MFMA flash attention (round-7 proven structure) + finer split-K + defer-max.
// Block = 1 head x 64 queries x kv-part. Item i in [0,77) per head:
//   i<24: np=4, qb=31-(i>>2)  | i<51: np=3, qb=25-(i-24)/3
//   i<69: np=2, qb=16-(i-51)/2| else: np=1, qb=7-(i-69)
// All parts are 2..9 tiles. Split items (i<69) write partials; sidx = h*69+i,
// stored in region A (sidx<768, old WcatT) or B.
// ---------------------------------------------------------------------------
__global__ __launch_bounds__(256) void attn_mfma(
    const unsigned short* __restrict__ Qc,
    const unsigned short* __restrict__ Kc,
    const unsigned short* __restrict__ Vg,
    unsigned short* __restrict__ attnO,
    unsigned short* __restrict__ OpA,
    unsigned short* __restrict__ OpB,
    float2* __restrict__ ml)
{
    __shared__ __align__(16) unsigned short KsL[2][64 * 64];
    __shared__ __align__(16) unsigned short VsL[2][64 * 64];
    __shared__ __align__(16) unsigned short Ps[64 * 64];

    const int h = blockIdx.y;
    int qb, part, np;
    {
        int i = blockIdx.x;
        if (i < 24)      { np = 4; qb = 31 - (i >> 2); part = i & 3; }
        else if (i < 51) { int j = i - 24; np = 3; qb = 25 - j / 3; part = j % 3; }
        else if (i < 69) { int j = i - 51; np = 2; qb = 16 - (j >> 1); part = j & 1; }
        else             { np = 1; qb = 7 - (blockIdx.x - 69); part = 0; }
    }
    const int nt = qb + 2;
    const int base = nt / np, rem = nt % np;
    const int t0 = part * base + (part < rem ? part : rem);
    const int t1 = t0 + base + (part < rem ? 1 : 0);

    const int q0 = qb * 64;
    const int tid = threadIdx.x, l = tid & 63, w = tid >> 6;
    const int lr = l & 15, lg = l >> 4;

    const int qrow = q0 + w * 16 + lr;
    bf16x8 qa0 = *(const bf16x8*)&Qc[((size_t)h * TSEQ + qrow) * 64 + lg * 8];
    bf16x8 qa1 = *(const bf16x8*)&Qc[((size_t)h * TSEQ + qrow) * 64 + 32 + lg * 8];

    const int sc8 = (((l & 7) ^ ((l >> 3) & 7))) * 8;
    const int r0s = (w * 2 + 0) * 8 + (l >> 3);
    const int r1s = (w * 2 + 1) * 8 + (l >> 3);
    const unsigned short* Kh = Kc + (((size_t)h * KST) << 6);
    const unsigned short* Vh = Vg + (size_t)h * 64 * KST;

#define STAGE_KV(bufi, fk0_) do {                                              \
        gload_lds16(Kh + (((size_t)((fk0_) + r0s)) << 6) + sc8,                \
                    &KsL[bufi][(w * 2 + 0) * 512]);                            \
        gload_lds16(Kh + (((size_t)((fk0_) + r1s)) << 6) + sc8,                \
                    &KsL[bufi][(w * 2 + 1) * 512]);                            \
        gload_lds16(Vh + (size_t)r0s * KST + (fk0_) + sc8,                     \
                    &VsL[bufi][(w * 2 + 0) * 512]);                            \
        gload_lds16(Vh + (size_t)r1s * KST + (fk0_) + sc8,                     \
                    &VsL[bufi][(w * 2 + 1) * 512]);                            \
    } while (0)

    f32x4 o[4];
    #pragma unroll
    for (int i = 0; i < 4; ++i) o[i] = (f32x4){0.f, 0.f, 0.f, 0.f};
    float m = -1e30f, ll = 0.0f;
    const int q = qrow;

    int buf = 0;
    STAGE_KV(0, t0 * 64);
    asm volatile("s_waitcnt vmcnt(0)" ::: "memory");
    __builtin_amdgcn_s_barrier();

    for (int kb = t0; kb < t1; ++kb) {
        const int fk0 = kb * 64;
        if (kb + 1 < t1) STAGE_KV(buf ^ 1, fk0 + 64);

        const unsigned short* Ksb = &KsL[buf][0];
        const unsigned short* Vsb = &VsL[buf][0];

        // ---- S^T = K Q^T
        f32x4 sa[4];
        #pragma unroll
        for (int i = 0; i < 4; ++i) sa[i] = (f32x4){0.f, 0.f, 0.f, 0.f};
        __builtin_amdgcn_s_setprio(1);
        #pragma unroll
        for (int ks = 0; ks < 2; ++ks) {
            int dd = lg * 8 + ks * 32;
            bf16x8 qa = ks ? qa1 : qa0;
            #pragma unroll
            for (int nf = 0; nf < 4; ++nf) {
                int kkc = nf * 16 + lr;
                bf16x8 kbf = *(const bf16x8*)&Ksb[kkc * 64 + (dd ^ ((kkc & 7) << 3))];
                sa[nf] = __builtin_amdgcn_mfma_f32_16x16x32_bf16(kbf, qa, sa[nf], 0, 0, 0);
            }
        }
        __builtin_amdgcn_s_setprio(0);

        // ---- mask; in-lane tree max + 2-stage shfl (Q pre-scaled)
        float sv[4][4];
        float mt = -1e30f;
        #pragma unroll
        for (int nf = 0; nf < 4; ++nf)
            #pragma unroll
            for (int reg = 0; reg < 4; ++reg) {
                int fk = fk0 + nf * 16 + lg * 4 + reg;
                float val = (fk <= q + 1) ? sa[nf][reg] : -1e9f;
                sv[nf][reg] = val;
                mt = fmaxf(mt, val);
            }
        mt = fmaxf(mt, __shfl_xor(mt, 16, 64));
        mt = fmaxf(mt, __shfl_xor(mt, 32, 64));
        // T13 defer-max: rescale only when the running max grows materially
        if (__any(mt > m + 8.0f)) {
            float mn = fmaxf(m, mt);
            float alpha = __expf(m - mn);
            m = mn;
            ll *= alpha;
            #pragma unroll
            for (int nf = 0; nf < 4; ++nf)
                #pragma unroll
                for (int reg = 0; reg < 4; ++reg)
                    o[nf][reg] *= alpha;
        }
        float rs = 0.0f;
        #pragma unroll
        for (int nf = 0; nf < 4; ++nf)
            #pragma unroll
            for (int reg = 0; reg < 4; ++reg) {
                float p = __expf(sv[nf][reg] - m);
                sv[nf][reg] = p;
                rs += p;
            }
        rs += __shfl_xor(rs, 16, 64);
        rs += __shfl_xor(rs, 32, 64);
        ll += rs;

        // ---- P -> bf16 -> LDS, packed b64 (wave-local rows: no barrier)
        {
            int r = w * 16 + lr;
            #pragma unroll
            for (int nf = 0; nf < 4; ++nf) {
                bf16x4 pk;
                pk[0] = f2bf(sv[nf][0]); pk[1] = f2bf(sv[nf][1]);
                pk[2] = f2bf(sv[nf][2]); pk[3] = f2bf(sv[nf][3]);
                int kk0 = nf * 16 + lg * 4;
                *(bf16x4*)&Ps[r * 64 + (kk0 ^ ((r & 7) << 3))] = pk;
            }
        }

        // ---- O^T += V^T P^T
        __builtin_amdgcn_s_setprio(1);
        #pragma unroll
        for (int ks = 0; ks < 2; ++ks) {
            int kk0 = lg * 8 + ks * 32;
            int pr  = w * 16 + lr;
            bf16x8 pa = *(const bf16x8*)&Ps[pr * 64 + (kk0 ^ ((pr & 7) << 3))];
            #pragma unroll
            for (int nf = 0; nf < 4; ++nf) {
                int dv = nf * 16 + lr;
                bf16x8 vb = *(const bf16x8*)&Vsb[dv * 64 + (kk0 ^ ((dv & 7) << 3))];
                o[nf] = __builtin_amdgcn_mfma_f32_16x16x32_bf16(vb, pa, o[nf], 0, 0, 0);
            }
        }
        __builtin_amdgcn_s_setprio(0);

        asm volatile("s_waitcnt vmcnt(0)" ::: "memory");
        __builtin_amdgcn_s_barrier();
        buf ^= 1;
    }
#undef STAGE_KV

    const float inv = 1.0f / ll;
    if (np == 1) {
        #pragma unroll
        for (int nf = 0; nf < 4; ++nf)
            #pragma unroll
            for (int reg = 0; reg < 4; ++reg) {
                int dv = nf * 16 + lg * 4 + reg;
                attnO[(size_t)q * DMODEL + h * 64 + dv] = f2bf(o[nf][reg] * inv);
            }
    } else {
        const int sidx = h * 69 + blockIdx.x;
        unsigned short* Od = (sidx < 768)
            ? OpA + (size_t)sidx * 4096
            : OpB + (size_t)(sidx - 768) * 4096;
        const int r = w * 16 + lr;
        #pragma unroll
        for (int nf = 0; nf < 4; ++nf)
            #pragma unroll
            for (int reg = 0; reg < 4; ++reg) {
                int dv = nf * 16 + lg * 4 + reg;
                Od[r * 64 + dv] = f2bf(o[nf][reg] * inv);
            }
        if (lg == 0)
            ml[sidx * 64 + r] = make_float2(m, ll);
    }
}

// ---------------------------------------------------------------------------
// Combine split partials: one block per (h, qb in [8,32)). np in {2,3,4}.
// ---------------------------------------------------------------------------
__global__ __launch_bounds__(256) void combine_wave(
    const unsigned short* __restrict__ OpA,
    const unsigned short* __restrict__ OpB,
    const float2* __restrict__ ml,
    unsigned short* __restrict__ attnO)
{
    const int qb = 8 + blockIdx.x;   // 8..31
    const int h  = blockIdx.y;
    int np, i0;
    if (qb >= 26)      { np = 4; i0 = (31 - qb) * 4; }
    else if (qb >= 17) { np = 3; i0 = 24 + (25 - qb) * 3; }
    else               { np = 2; i0 = 51 + (16 - qb) * 2; }
    const int sidx0 = h * 69 + i0;

    const int t = threadIdx.x;
    const int r = t >> 2, dv0 = (t & 3) * 16;

    float wt[4];
    float mm = -1e30f;
    #pragma unroll
    for (int p = 0; p < 4; ++p) {
        wt[p] = 0.0f;
        if (p < np) {
            float2 v = ml[(sidx0 + p) * 64 + r];
            wt[p] = v.x;  // temp: store m
            mm = fmaxf(mm, v.x);
        }
    }
    float tot = 0.0f;
    #pragma unroll
    for (int p = 0; p < 4; ++p) {
        if (p < np) {
            float2 v = ml[(sidx0 + p) * 64 + r];
            wt[p] = v.y * __expf(v.x - mm);
            tot += wt[p];
        }
    }
    const float inv = 1.0f / tot;

    float accv[16];
    #pragma unroll
    for (int c = 0; c < 16; ++c) accv[c] = 0.0f;
    #pragma unroll
    for (int p = 0; p < 4; ++p) {
        if (p < np) {
            int s = sidx0 + p;
            const unsigned short* Od = (s < 768)
                ? OpA + (size_t)s * 4096
                : OpB + (size_t)(s - 768) * 4096;
            #pragma unroll
            for (int c4 = 0; c4 < 4; ++c4) {
                ushort4 v = *(const ushort4*)&Od[r * 64 + dv0 + c4 * 4];
                accv[c4 * 4 + 0] += wt[p] * bf2f(v.x);
                accv[c4 * 4 + 1] += wt[p] * bf2f(v.y);
                accv[c4 * 4 + 2] += wt[p] * bf2f(v.z);
                accv[c4 * 4 + 3] += wt[p] * bf2f(v.w);
            }
        }
    }
    const int q = qb * 64 + r;
    #pragma unroll
    for (int c4 = 0; c4 < 4; ++c4) {
        ushort4 ov;
        ov.x = f2bf(accv[c4 * 4 + 0] * inv);
        ov.y = f2bf(accv[c4 * 4 + 1] * inv);
        ov.z = f2bf(accv[c4 * 4 + 2] * inv);
        ov.w = f2bf(accv[c4 * 4 + 3] * inv);
        *(ushort4*)&attnO[(size_t)q * DMODEL + h * 64 + dv0 + c4 * 4] = ov;
    }
}

// ---------------------------------------------------------------------------
extern "C" void kernel_launch(void* const* d_in, const int* in_sizes, int n_in,
                              void* d_out, int out_size, void* d_ws, size_t ws_size,
                              hipStream_t stream)
{
    const float* x      = (const float*)d_in[0];
    const float* wq_sem = (const float*)d_in[1];
    const float* wk_sem = (const float*)d_in[2];
    const float* wq_geo = (const float*)d_in[3];
    const float* wk_geo = (const float*)d_in[4];
    const float* wv     = (const float*)d_in[5];
    const float* wo     = (const float*)d_in[6];
    const float* ksn    = (const float*)d_in[7];
    const float* kgn    = (const float*)d_in[8];
    const float* vn     = (const float*)d_in[9];
    float* out = (float*)d_out;

    // Workspace (peak 28.8 MiB):
    //  [0,        4.19M)  Xb -> attnO
    //  [4.19M,   10.49M)  WcatT -> OpA (768 partials x 8KB)
    //  [10.49M,  12.58M)  WoT
    //  [12.58M,  16.78M)  Qc  [16][2048][64]
    //  [16.78M,  21.10M)  Kc  [16][2112][64]
    //  [21.10M,  25.43M)  Vg  [16][64][2112]
    //  [25.43M,  28.18M)  OpB (336 partials x 8KB)
    //  [28.18M,  28.75M)  ml  float2 [1104][64]
    char* ws = (char*)d_ws;
    unsigned short* Xb    = (unsigned short*)(ws);
    unsigned short* attnO = (unsigned short*)(ws);
    unsigned short* WcatT = (unsigned short*)(ws + 4194304);
    unsigned short* OpA   = (unsigned short*)(ws + 4194304);
    unsigned short* WoT   = (unsigned short*)(ws + 10485760);
    unsigned short* Qc    = (unsigned short*)(ws + 12582912);
    unsigned short* Kc    = (unsigned short*)(ws + 16777216);
    unsigned short* Vg    = (unsigned short*)(ws + 21102592);
    unsigned short* OpB   = (unsigned short*)(ws + 25427968);
    float2*         ml    = (float2*)(ws + 28180480);

    convert_x<<<2048, 256, 0, stream>>>(x, Xb);
    transpose_all<<<dim3(16, 16, 6), 256, 0, stream>>>(
        wq_sem, wk_sem, wq_geo, wk_geo, wv, wo, WcatT, WoT);
    init_null<<<16, 256, 0, stream>>>(ksn, kgn, vn, Kc, Vg);

    gemm_proj_fused<<<dim3(24, 32), 256, 0, stream>>>(Xb, WcatT, Qc, Kc, Vg);

    attn_mfma<<<dim3(77, NHEAD), 256, 0, stream>>>(Qc, Kc, Vg, attnO, OpA, OpB, ml);
    combine_wave<<<dim3(24, NHEAD), 256, 0, stream>>>(OpA, OpB, ml, attnO);

    gemm_out<<<dim3(16, 32), 256, 0, stream>>>(attnO, WoT, out);
}